// Round 5
// baseline (454.344 us; speedup 1.0000x reference)
//
#include <hip/hip_runtime.h>
#include <stdint.h>

#define NHEAD  16
#define SEQ    2048
#define DMODEL 1024
#define BATCH  4

typedef __attribute__((ext_vector_type(4))) float f32x4;
typedef __attribute__((ext_vector_type(8))) __bf16 bf16x8;
typedef __attribute__((ext_vector_type(8))) unsigned short u16x8;

__device__ __forceinline__ unsigned short f2bf(float f) {
    unsigned int u = __builtin_bit_cast(unsigned int, f);
    u += 0x7FFFu + ((u >> 16) & 1u);   // RNE
    return (unsigned short)(u >> 16);
}

__device__ __forceinline__ unsigned int cvt_pk_bf16(float lo, float hi) {
    unsigned int r;
    asm("v_cvt_pk_bf16_f32 %0, %1, %2" : "=v"(r) : "v"(lo), "v"(hi));
    return r;
}

// async global->LDS, 16B per lane. LDS dest must be wave-uniform base + lane*16.
__device__ __forceinline__ void gload_lds16(const void* g, void* l) {
    __builtin_amdgcn_global_load_lds(
        (const __attribute__((address_space(1))) unsigned int*)(uintptr_t)g,
        (__attribute__((address_space(3))) unsigned int*)(uintptr_t)l,
        16, 0, 0);
}

__device__ __forceinline__ bf16x8 lds_frag(const unsigned short* p) {
    return __builtin_bit_cast(bf16x8, *(const u16x8*)p);
}

__device__ __forceinline__ bf16x8 gfrag(const unsigned short* p) {
    return __builtin_bit_cast(bf16x8, *(const u16x8*)p);
}

// ---------------- fp32 -> bf16 conversion ----------------
__global__ __launch_bounds__(256) void cvt_f32_bf16(const float* __restrict__ src,
                                                    unsigned short* __restrict__ dst, int n4) {
    int i = blockIdx.x * 256 + threadIdx.x;
    if (i < n4) {
        float4 v = ((const float4*)src)[i];
        ushort4 o;
        o.x = f2bf(v.x); o.y = f2bf(v.y); o.z = f2bf(v.z); o.w = f2bf(v.w);
        ((ushort4*)dst)[i] = o;
    }
}

__global__ __launch_bounds__(256) void cvt_weights(const float* __restrict__ w0,
                                                   const float* __restrict__ w1,
                                                   const float* __restrict__ w2,
                                                   const float* __restrict__ w3,
                                                   unsigned short* __restrict__ dst) {
    int which = blockIdx.x >> 10;
    int i = (blockIdx.x & 1023) * 256 + threadIdx.x;
    const float* src = which == 0 ? w0 : which == 1 ? w1 : which == 2 ? w2 : w3;
    unsigned short* d = dst + (size_t)which * 1024 * 1024;
    float4 v = ((const float4*)src)[i];
    ushort4 o;
    o.x = f2bf(v.x); o.y = f2bf(v.y); o.z = f2bf(v.z); o.w = f2bf(v.w);
    ((ushort4*)d)[i] = o;
}

// ---------------- fused QKV GEMM: [Q|K|V] = X(8192x1024) * Wcat(3072x1024)^T ----------------
// grid (24, 64): x = n-tile (0-7 Q, 8-15 K, 16-23 V), y = m-tile
// Q output is pre-scaled by 1/8*log2(e) so flash softmax works directly in log2 domain.
__global__ __launch_bounds__(256) void gemm_qkv(const unsigned short* __restrict__ A,
                                                const unsigned short* __restrict__ Wc,
                                                unsigned short* __restrict__ qw,
                                                unsigned short* __restrict__ kw,
                                                unsigned short* __restrict__ vw) {
    __shared__ __align__(16) unsigned short As[2][128 * 64];
    __shared__ __align__(16) unsigned short Bs[2][128 * 64];

    const int tid  = threadIdx.x;
    const int lane = tid & 63;
    const int wid  = tid >> 6;
    const int wm = wid >> 1, wn = wid & 1;
    const int l15 = lane & 15, lg = lane >> 4;

    const int tn = blockIdx.x;
    const int m0 = blockIdx.y * 128, n0 = tn * 128;

    f32x4 acc[4][4];
#pragma unroll
    for (int i = 0; i < 4; i++)
#pragma unroll
        for (int j = 0; j < 4; j++) acc[i][j] = f32x4{0.f, 0.f, 0.f, 0.f};

    const int e0 = tid * 8;
    auto STAGE = [&](int kk, int bufi) {
#pragma unroll
        for (int is = 0; is < 4; ++is) {
            int e = is * 2048 + e0;
            int row = e >> 6, col = e & 63;
            gload_lds16(A  + (size_t)(m0 + row) * 1024 + kk + col, &As[bufi][e]);
            gload_lds16(Wc + (size_t)(n0 + row) * 1024 + kk + col, &Bs[bufi][e]);
        }
    };

    STAGE(0, 0);
    __syncthreads();

    for (int kk = 0; kk < 1024; kk += 64) {
        const int cur = (kk >> 6) & 1;
        if (kk + 64 < 1024) STAGE(kk + 64, cur ^ 1);
#pragma unroll
        for (int ks = 0; ks < 2; ++ks) {
            bf16x8 a[4], b[4];
#pragma unroll
            for (int f = 0; f < 4; f++) {
                a[f] = lds_frag(&As[cur][(wm * 64 + f * 16 + l15) * 64 + ks * 32 + lg * 8]);
                b[f] = lds_frag(&Bs[cur][(wn * 64 + f * 16 + l15) * 64 + ks * 32 + lg * 8]);
            }
#pragma unroll
            for (int i = 0; i < 4; i++)
#pragma unroll
                for (int j = 0; j < 4; j++)
                    acc[i][j] = __builtin_amdgcn_mfma_f32_16x16x32_bf16(a[i], b[j], acc[i][j], 0, 0, 0);
        }
        __syncthreads();
    }

    if (tn >= 16) {   // V -> (b,h,dk,s) transposed
        unsigned short* out = vw;
#pragma unroll
        for (int i = 0; i < 4; i++)
#pragma unroll
            for (int r = 0; r < 4; r++) {
                int m = m0 + wm * 64 + i * 16 + lg * 4 + r;
                int b = m >> 11, s = m & 2047;
#pragma unroll
                for (int j = 0; j < 4; j++) {
                    int n = n0 + wn * 64 + j * 16 + l15;
                    int h = (n >> 6) & 15, dk = n & 63;
                    out[((size_t)(b * NHEAD + h) * 64 + dk) * SEQ + s] = f2bf(acc[i][j][r]);
                }
            }
    } else {          // Q or K with RoPE -> (b,h,s,dk)
        unsigned short* out = (tn < 8) ? qw : kw;
        const float qscale = (tn < 8) ? 0.18033688011112042f : 1.0f;   // 1/8*log2(e) for Q
        const float L2T = 13.287712379549449f;   // log2(10000)
        float invf[4];
#pragma unroll
        for (int j = 0; j < 4; j++) {
            int idx = j * 16 + l15;          // n % 64
            int t = idx >> 1;
            invf[j] = exp2f(-((float)(2 * t) * (1.0f / 64.0f)) * L2T);
        }
        const int par = l15 & 1;
#pragma unroll
        for (int i = 0; i < 4; i++)
#pragma unroll
            for (int r = 0; r < 4; r++) {
                int m = m0 + wm * 64 + i * 16 + lg * 4 + r;
                int b = m >> 11, s = m & 2047;
                float fs = (float)s;
#pragma unroll
                for (int j = 0; j < 4; j++) {
                    float v = acc[i][j][r];
                    float other = __shfl_xor(v, 1);
                    float sn, cs;
                    __sincosf(fs * invf[j], &sn, &cs);
                    float y = par ? fmaf(v, cs, other * sn) : fmaf(v, cs, -other * sn);
                    y *= qscale;
                    int n = n0 + wn * 64 + j * 16 + l15;
                    int h = (n >> 6) & 15, dk = n & 63;
                    out[((size_t)(b * NHEAD + h) * SEQ + s) * 64 + dk] = f2bf(y);
                }
            }
    }
}

// ---------------- output GEMM: d_out = OW(8192x1024) * Wo(1024x1024)^T, fp32 out ----------------
__global__ __launch_bounds__(256) void gemm_out(const unsigned short* __restrict__ A,
                                                const unsigned short* __restrict__ W,
                                                float* __restrict__ out) {
    __shared__ __align__(16) unsigned short As[2][128 * 64];
    __shared__ __align__(16) unsigned short Bs[2][128 * 64];

    const int tid  = threadIdx.x;
    const int lane = tid & 63;
    const int wid  = tid >> 6;
    const int wm = wid >> 1, wn = wid & 1;
    const int l15 = lane & 15, lg = lane >> 4;

    const int tn = blockIdx.x & 7;
    const int tm = blockIdx.x >> 3;
    const int m0 = tm * 128, n0 = tn * 128;

    f32x4 acc[4][4];
#pragma unroll
    for (int i = 0; i < 4; i++)
#pragma unroll
        for (int j = 0; j < 4; j++) acc[i][j] = f32x4{0.f, 0.f, 0.f, 0.f};

    const int e0 = tid * 8;
    auto STAGE = [&](int kk, int bufi) {
#pragma unroll
        for (int is = 0; is < 4; ++is) {
            int e = is * 2048 + e0;
            int row = e >> 6, col = e & 63;
            gload_lds16(A + (size_t)(m0 + row) * 1024 + kk + col, &As[bufi][e]);
            gload_lds16(W + (size_t)(n0 + row) * 1024 + kk + col, &Bs[bufi][e]);
        }
    };

    STAGE(0, 0);
    __syncthreads();

    for (int kk = 0; kk < 1024; kk += 64) {
        const int cur = (kk >> 6) & 1;
        if (kk + 64 < 1024) STAGE(kk + 64, cur ^ 1);
#pragma unroll
        for (int ks = 0; ks < 2; ++ks) {
            bf16x8 a[4], b[4];
#pragma unroll
            for (int f = 0; f < 4; f++) {
                a[f] = lds_frag(&As[cur][(wm * 64 + f * 16 + l15) * 64 + ks * 32 + lg * 8]);
                b[f] = lds_frag(&Bs[cur][(wn * 64 + f * 16 + l15) * 64 + ks * 32 + lg * 8]);
            }
#pragma unroll
            for (int i = 0; i < 4; i++)
#pragma unroll
                for (int j = 0; j < 4; j++)
                    acc[i][j] = __builtin_amdgcn_mfma_f32_16x16x32_bf16(a[i], b[j], acc[i][j], 0, 0, 0);
        }
        __syncthreads();
    }

#pragma unroll
    for (int i = 0; i < 4; i++)
#pragma unroll
        for (int r = 0; r < 4; r++) {
            int m = m0 + wm * 64 + i * 16 + lg * 4 + r;
            float* orow = out + (size_t)m * 1024 + n0 + wn * 64 + l15;
#pragma unroll
            for (int j = 0; j < 4; j++) orow[j * 16] = acc[i][j][r];
        }
}

// ---------------- causal flash attention: barrier-free, K/V direct from L2 ----------------
// Q,K in (bh, s, dk) (Q pre-scaled by 1/8*log2e); V in (bh, dk, s). Out (b,s,dmodel) bf16.
// No K/V LDS staging (K/V working set per XCD ~4MB = L2-resident). Only per-wave Ps.
__global__ __launch_bounds__(256, 5) void flash_attn(const unsigned short* __restrict__ Qw,
                                                     const unsigned short* __restrict__ Kw,
                                                     const unsigned short* __restrict__ Vw,
                                                     unsigned short* __restrict__ Ow) {
    __shared__ __align__(16) unsigned short Ps[4][16 * 64];   // per-wave P^T buffer, 8KB total

    const int tid  = threadIdx.x;
    const int lane = tid & 63;
    const int w    = tid >> 6;
    const int l15 = lane & 15, lg = lane >> 4;
    const int l7 = l15 & 7;

    // XCD-aware swizzle: 8 consecutive bh per XCD (K/V set = 4MB = L2), heavy-qb-first
    const int logical = (blockIdx.x & 7) * 256 + (blockIdx.x >> 3);
    const int bh = logical >> 5;
    const int qb = 31 - (logical & 31);

    const unsigned short* Kbh = Kw + (size_t)bh * (SEQ * 64);
    const unsigned short* Vbh = Vw + (size_t)bh * (64 * SEQ);

    const int qrow0 = w * 16;          // wave's q range within the 64-row block
    const int prow  = qrow0 + l15;     // this lane's softmax q (block-local)

    // Q fragments in registers (loop-invariant): q = prow, dk = ks*32 + lg*8 .. +7
    const unsigned short* Qrow = Qw + (size_t)bh * (SEQ * 64) + (size_t)(qb * 64 + prow) * 64;
    bf16x8 qf0 = gfrag(Qrow + lg * 8);
    bf16x8 qf1 = gfrag(Qrow + 32 + lg * 8);

    f32x4 oacc[4];   // oacc[f][r]: O[q=qrow0+4lg+r][dk=16f+l15]
#pragma unroll
    for (int f = 0; f < 4; f++) oacc[f] = f32x4{0.f, 0.f, 0.f, 0.f};
    float mrun = -3.0e38f, lrun = 0.f;   // for q = prow (log2 domain)

    unsigned short* pbase = &Ps[w][l15 * 64];
    const unsigned short* prd = &Ps[w][l15 * 64];

    for (int kt = 0; kt <= qb; ++kt) {
        // per-iter K base: row (kt*64 + f*16 + l15), col ks*32+lg*8
        const unsigned short* Kt = Kbh + (size_t)kt * 4096 + l15 * 64 + lg * 8;

        // S^T tiles: st[f] = mfma(K_f, Q): lane holds S[kv=16f+4lg+r][q=prow]
        f32x4 st[4];
#pragma unroll
        for (int f = 0; f < 4; f++) st[f] = f32x4{0.f, 0.f, 0.f, 0.f};
        __builtin_amdgcn_s_setprio(1);
#pragma unroll
        for (int ks = 0; ks < 2; ++ks) {
            bf16x8 qk = (ks == 0) ? qf0 : qf1;
#pragma unroll
            for (int f = 0; f < 4; f++) {
                bf16x8 kfrag = gfrag(Kt + f * 1024 + ks * 32);
                st[f] = __builtin_amdgcn_mfma_f32_16x16x32_bf16(kfrag, qk, st[f], 0, 0, 0);
            }
        }
        __builtin_amdgcn_s_setprio(0);

        // causal mask on diag tile (scores already in log2 domain via pre-scaled Q)
        if (kt == qb) {
#pragma unroll
            for (int f = 0; f < 4; f++)
#pragma unroll
                for (int r = 0; r < 4; r++) {
                    int kv = f * 16 + 4 * lg + r;
                    if (kv > prow) st[f][r] = -3.0e38f;
                }
        }

        // per-q max: 15 in-lane + 2 shuffles
        float pm = fmaxf(fmaxf(fmaxf(st[0][0], st[0][1]), fmaxf(st[0][2], st[0][3])),
                         fmaxf(fmaxf(st[1][0], st[1][1]), fmaxf(st[1][2], st[1][3])));
        pm = fmaxf(pm, fmaxf(fmaxf(fmaxf(st[2][0], st[2][1]), fmaxf(st[2][2], st[2][3])),
                             fmaxf(fmaxf(st[3][0], st[3][1]), fmaxf(st[3][2], st[3][3]))));
        pm = fmaxf(pm, __shfl_xor(pm, 16));
        pm = fmaxf(pm, __shfl_xor(pm, 32));

        // defer-max (T13): only rescale when some row grew by > 8 (log2 domain)
        if (!__all(pm - mrun <= 8.0f)) {
            float mnew = fmaxf(mrun, pm);
            float sc0 = exp2f(mrun - mnew);
            mrun = mnew;
            lrun *= sc0;
#pragma unroll
            for (int r = 0; r < 4; r++) {
                float so = __shfl(sc0, lg * 4 + r);   // sc for q = qrow0+4lg+r
#pragma unroll
                for (int f = 0; f < 4; f++) oacc[f][r] *= so;
            }
        }

        // exp2 + row-sum
        float lsum = 0.f;
#pragma unroll
        for (int f = 0; f < 4; f++)
#pragma unroll
            for (int r = 0; r < 4; r++) {
                float e = exp2f(st[f][r] - mrun);
                st[f][r] = e;
                lsum += e;
            }
        lsum += __shfl_xor(lsum, 16);
        lsum += __shfl_xor(lsum, 32);
        lrun += lsum;

        // P -> Ps (bf16, packed b64 writes, swizzled); row = l15 (wave-private, no barrier)
        {
            const int halfoff = (lg & 1) << 2;
            const int cbase = lg >> 1;
#pragma unroll
            for (int f = 0; f < 4; f++) {
                uint2 pw;
                pw.x = cvt_pk_bf16(st[f][0], st[f][1]);
                pw.y = cvt_pk_bf16(st[f][2], st[f][3]);
                *(uint2*)(pbase + (((2 * f + cbase) ^ l7) << 3) + halfoff) = pw;
            }
        }

        // O += P V  (A = P rows from Ps, B = V^T fragments direct from global/L2)
        const unsigned short* Vt = Vbh + (size_t)l15 * SEQ + kt * 64 + lg * 8;
        __builtin_amdgcn_s_setprio(1);
#pragma unroll
        for (int ks = 0; ks < 2; ++ks) {
            bf16x8 pa = lds_frag(prd + (((ks * 4 + lg) ^ l7) << 3));
#pragma unroll
            for (int f = 0; f < 4; f++) {
                bf16x8 vb = gfrag(Vt + (size_t)f * 16 * SEQ + ks * 32);
                oacc[f] = __builtin_amdgcn_mfma_f32_16x16x32_bf16(pa, vb, oacc[f], 0, 0, 0);
            }
        }
        __builtin_amdgcn_s_setprio(0);
    }

    const int b = bh >> 4, h = bh & 15;
#pragma unroll
    for (int r = 0; r < 4; r++) {
        float lr = __shfl(lrun, lg * 4 + r);   // l for q = qrow0+4lg+r
        float inv = 1.0f / lr;
        int sg = qb * 64 + qrow0 + lg * 4 + r;
        unsigned short* orow = Ow + ((size_t)(b * SEQ + sg) * DMODEL) + h * 64 + l15;
#pragma unroll
        for (int f = 0; f < 4; f++) orow[f * 16] = f2bf(oacc[f][r] * inv);
    }
}

extern "C" void kernel_launch(void* const* d_in, const int* in_sizes, int n_in,
                              void* d_out, int out_size, void* d_ws, size_t ws_size,
                              hipStream_t stream) {
    const float* x  = (const float*)d_in[0];
    const float* wq = (const float*)d_in[1];
    const float* wk = (const float*)d_in[2];
    const float* wv = (const float*)d_in[3];
    const float* wo = (const float*)d_in[4];

    unsigned short* ws = (unsigned short*)d_ws;
    const size_t MEL = (size_t)8192 * 1024;   // 8M elements
    const size_t WEL = (size_t)1024 * 1024;   // 1M elements
    unsigned short* xb  = ws;
    unsigned short* wqb = xb + MEL;           // 4 weights contiguous: wq|wk|wv|wo
    unsigned short* wob = wqb + 3 * WEL;
    unsigned short* qw  = wob + WEL;
    unsigned short* kw  = qw + MEL;
    unsigned short* vw  = kw + MEL;
    unsigned short* ow  = vw + MEL;

    cvt_f32_bf16<<<8192, 256, 0, stream>>>(x, xb, (int)(MEL / 4));
    cvt_weights<<<4096, 256, 0, stream>>>(wq, wk, wv, wo, wqb);

    gemm_qkv<<<dim3(24, 64), 256, 0, stream>>>(xb, wqb, qw, kw, vw);

    flash_attn<<<4 * NHEAD * 32, 256, 0, stream>>>(qw, kw, vw, ow);

    gemm_out<<<512, 256, 0, stream>>>(ow, wob, (float*)d_out);
}

// Round 6
// 230.926 us; speedup vs baseline: 1.9675x; 1.9675x over previous
//
#include <hip/hip_runtime.h>
#include <stdint.h>

#define NHEAD  16
#define SEQ    2048
#define DMODEL 1024
#define BATCH  4

typedef __attribute__((ext_vector_type(4))) float f32x4;
typedef __attribute__((ext_vector_type(8))) __bf16 bf16x8;
typedef __attribute__((ext_vector_type(8))) unsigned short u16x8;

__device__ __forceinline__ unsigned short f2bf(float f) {
    unsigned int u = __builtin_bit_cast(unsigned int, f);
    u += 0x7FFFu + ((u >> 16) & 1u);   // RNE
    return (unsigned short)(u >> 16);
}

__device__ __forceinline__ unsigned int cvt_pk_bf16(float lo, float hi) {
    unsigned int r;
    asm("v_cvt_pk_bf16_f32 %0, %1, %2" : "=v"(r) : "v"(lo), "v"(hi));
    return r;
}

// async global->LDS, 16B per lane. LDS dest must be wave-uniform base + lane*16.
__device__ __forceinline__ void gload_lds16(const void* g, void* l) {
    __builtin_amdgcn_global_load_lds(
        (const __attribute__((address_space(1))) unsigned int*)(uintptr_t)g,
        (__attribute__((address_space(3))) unsigned int*)(uintptr_t)l,
        16, 0, 0);
}

__device__ __forceinline__ bf16x8 lds_frag(const unsigned short* p) {
    return __builtin_bit_cast(bf16x8, *(const u16x8*)p);
}

__device__ __forceinline__ bf16x8 gfrag(const unsigned short* p) {
    return __builtin_bit_cast(bf16x8, *(const u16x8*)p);
}

// ---------------- fp32 -> bf16 conversion ----------------
__global__ __launch_bounds__(256) void cvt_f32_bf16(const float* __restrict__ src,
                                                    unsigned short* __restrict__ dst, int n4) {
    int i = blockIdx.x * 256 + threadIdx.x;
    if (i < n4) {
        float4 v = ((const float4*)src)[i];
        ushort4 o;
        o.x = f2bf(v.x); o.y = f2bf(v.y); o.z = f2bf(v.z); o.w = f2bf(v.w);
        ((ushort4*)dst)[i] = o;
    }
}

__global__ __launch_bounds__(256) void cvt_weights(const float* __restrict__ w0,
                                                   const float* __restrict__ w1,
                                                   const float* __restrict__ w2,
                                                   const float* __restrict__ w3,
                                                   unsigned short* __restrict__ dst) {
    int which = blockIdx.x >> 10;
    int i = (blockIdx.x & 1023) * 256 + threadIdx.x;
    const float* src = which == 0 ? w0 : which == 1 ? w1 : which == 2 ? w2 : w3;
    unsigned short* d = dst + (size_t)which * 1024 * 1024;
    float4 v = ((const float4*)src)[i];
    ushort4 o;
    o.x = f2bf(v.x); o.y = f2bf(v.y); o.z = f2bf(v.z); o.w = f2bf(v.w);
    ((ushort4*)d)[i] = o;
}

// ---------------- fused QKV GEMM: [Q|K|V] = X(8192x1024) * Wcat(3072x1024)^T ----------------
// grid (24, 64): x = n-tile (0-7 Q, 8-15 K, 16-23 V), y = m-tile
// Q output is pre-scaled by 1/8*log2(e) so flash softmax works directly in log2 domain.
__global__ __launch_bounds__(256) void gemm_qkv(const unsigned short* __restrict__ A,
                                                const unsigned short* __restrict__ Wc,
                                                unsigned short* __restrict__ qw,
                                                unsigned short* __restrict__ kw,
                                                unsigned short* __restrict__ vw) {
    __shared__ __align__(16) unsigned short As[2][128 * 64];
    __shared__ __align__(16) unsigned short Bs[2][128 * 64];

    const int tid  = threadIdx.x;
    const int lane = tid & 63;
    const int wid  = tid >> 6;
    const int wm = wid >> 1, wn = wid & 1;
    const int l15 = lane & 15, lg = lane >> 4;

    const int tn = blockIdx.x;
    const int m0 = blockIdx.y * 128, n0 = tn * 128;

    f32x4 acc[4][4];
#pragma unroll
    for (int i = 0; i < 4; i++)
#pragma unroll
        for (int j = 0; j < 4; j++) acc[i][j] = f32x4{0.f, 0.f, 0.f, 0.f};

    const int e0 = tid * 8;
    auto STAGE = [&](int kk, int bufi) {
#pragma unroll
        for (int is = 0; is < 4; ++is) {
            int e = is * 2048 + e0;
            int row = e >> 6, col = e & 63;
            gload_lds16(A  + (size_t)(m0 + row) * 1024 + kk + col, &As[bufi][e]);
            gload_lds16(Wc + (size_t)(n0 + row) * 1024 + kk + col, &Bs[bufi][e]);
        }
    };

    STAGE(0, 0);
    __syncthreads();

    for (int kk = 0; kk < 1024; kk += 64) {
        const int cur = (kk >> 6) & 1;
        if (kk + 64 < 1024) STAGE(kk + 64, cur ^ 1);
#pragma unroll
        for (int ks = 0; ks < 2; ++ks) {
            bf16x8 a[4], b[4];
#pragma unroll
            for (int f = 0; f < 4; f++) {
                a[f] = lds_frag(&As[cur][(wm * 64 + f * 16 + l15) * 64 + ks * 32 + lg * 8]);
                b[f] = lds_frag(&Bs[cur][(wn * 64 + f * 16 + l15) * 64 + ks * 32 + lg * 8]);
            }
#pragma unroll
            for (int i = 0; i < 4; i++)
#pragma unroll
                for (int j = 0; j < 4; j++)
                    acc[i][j] = __builtin_amdgcn_mfma_f32_16x16x32_bf16(a[i], b[j], acc[i][j], 0, 0, 0);
        }
        __syncthreads();
    }

    if (tn >= 16) {   // V -> (b,h,dk,s) transposed
        unsigned short* out = vw;
#pragma unroll
        for (int i = 0; i < 4; i++)
#pragma unroll
            for (int r = 0; r < 4; r++) {
                int m = m0 + wm * 64 + i * 16 + lg * 4 + r;
                int b = m >> 11, s = m & 2047;
#pragma unroll
                for (int j = 0; j < 4; j++) {
                    int n = n0 + wn * 64 + j * 16 + l15;
                    int h = (n >> 6) & 15, dk = n & 63;
                    out[((size_t)(b * NHEAD + h) * 64 + dk) * SEQ + s] = f2bf(acc[i][j][r]);
                }
            }
    } else {          // Q or K with RoPE -> (b,h,s,dk)
        unsigned short* out = (tn < 8) ? qw : kw;
        const float qscale = (tn < 8) ? 0.18033688011112042f : 1.0f;   // 1/8*log2(e) for Q
        const float L2T = 13.287712379549449f;   // log2(10000)
        float invf[4];
#pragma unroll
        for (int j = 0; j < 4; j++) {
            int idx = j * 16 + l15;          // n % 64
            int t = idx >> 1;
            invf[j] = exp2f(-((float)(2 * t) * (1.0f / 64.0f)) * L2T);
        }
        const int par = l15 & 1;
#pragma unroll
        for (int i = 0; i < 4; i++)
#pragma unroll
            for (int r = 0; r < 4; r++) {
                int m = m0 + wm * 64 + i * 16 + lg * 4 + r;
                int b = m >> 11, s = m & 2047;
                float fs = (float)s;
#pragma unroll
                for (int j = 0; j < 4; j++) {
                    float v = acc[i][j][r];
                    float other = __shfl_xor(v, 1);
                    float sn, cs;
                    __sincosf(fs * invf[j], &sn, &cs);
                    float y = par ? fmaf(v, cs, other * sn) : fmaf(v, cs, -other * sn);
                    y *= qscale;
                    int n = n0 + wn * 64 + j * 16 + l15;
                    int h = (n >> 6) & 15, dk = n & 63;
                    out[((size_t)(b * NHEAD + h) * SEQ + s) * 64 + dk] = f2bf(y);
                }
            }
    }
}

// ---------------- output GEMM: d_out = OW(8192x1024) * Wo(1024x1024)^T, fp32 out ----------------
__global__ __launch_bounds__(256) void gemm_out(const unsigned short* __restrict__ A,
                                                const unsigned short* __restrict__ W,
                                                float* __restrict__ out) {
    __shared__ __align__(16) unsigned short As[2][128 * 64];
    __shared__ __align__(16) unsigned short Bs[2][128 * 64];

    const int tid  = threadIdx.x;
    const int lane = tid & 63;
    const int wid  = tid >> 6;
    const int wm = wid >> 1, wn = wid & 1;
    const int l15 = lane & 15, lg = lane >> 4;

    const int tn = blockIdx.x & 7;
    const int tm = blockIdx.x >> 3;
    const int m0 = tm * 128, n0 = tn * 128;

    f32x4 acc[4][4];
#pragma unroll
    for (int i = 0; i < 4; i++)
#pragma unroll
        for (int j = 0; j < 4; j++) acc[i][j] = f32x4{0.f, 0.f, 0.f, 0.f};

    const int e0 = tid * 8;
    auto STAGE = [&](int kk, int bufi) {
#pragma unroll
        for (int is = 0; is < 4; ++is) {
            int e = is * 2048 + e0;
            int row = e >> 6, col = e & 63;
            gload_lds16(A + (size_t)(m0 + row) * 1024 + kk + col, &As[bufi][e]);
            gload_lds16(W + (size_t)(n0 + row) * 1024 + kk + col, &Bs[bufi][e]);
        }
    };

    STAGE(0, 0);
    __syncthreads();

    for (int kk = 0; kk < 1024; kk += 64) {
        const int cur = (kk >> 6) & 1;
        if (kk + 64 < 1024) STAGE(kk + 64, cur ^ 1);
#pragma unroll
        for (int ks = 0; ks < 2; ++ks) {
            bf16x8 a[4], b[4];
#pragma unroll
            for (int f = 0; f < 4; f++) {
                a[f] = lds_frag(&As[cur][(wm * 64 + f * 16 + l15) * 64 + ks * 32 + lg * 8]);
                b[f] = lds_frag(&Bs[cur][(wn * 64 + f * 16 + l15) * 64 + ks * 32 + lg * 8]);
            }
#pragma unroll
            for (int i = 0; i < 4; i++)
#pragma unroll
                for (int j = 0; j < 4; j++)
                    acc[i][j] = __builtin_amdgcn_mfma_f32_16x16x32_bf16(a[i], b[j], acc[i][j], 0, 0, 0);
        }
        __syncthreads();
    }

#pragma unroll
    for (int i = 0; i < 4; i++)
#pragma unroll
        for (int r = 0; r < 4; r++) {
            int m = m0 + wm * 64 + i * 16 + lg * 4 + r;
            float* orow = out + (size_t)m * 1024 + n0 + wn * 64 + l15;
#pragma unroll
            for (int j = 0; j < 4; j++) orow[j * 16] = acc[i][j][r];
        }
}

// ---------------- causal flash attention: 128 q-rows/block, dual sub-tile ----------------
// Q,K in (bh, s, dk) (Q pre-scaled by 1/8*log2e); V in (bh, dk, s). Out (b,s,dmodel) bf16.
// K/V LDS double-buffered + XOR-swizzled (chunk c of row -> c ^ (row&7)).
// Two 64-row q sub-tiles (A, B) share each staged K/V tile; Ps reused A-then-B (wave-private).
__global__ __launch_bounds__(256, 4) void flash_attn(const unsigned short* __restrict__ Qw,
                                                     const unsigned short* __restrict__ Kw,
                                                     const unsigned short* __restrict__ Vw,
                                                     unsigned short* __restrict__ Ow) {
    __shared__ __align__(16) unsigned short Ks[2][64 * 64];
    __shared__ __align__(16) unsigned short Vs[2][64 * 64];   // [dk][kv]
    __shared__ __align__(16) unsigned short Ps[64 * 64];      // [q][kv], swizzled, reused A/B
    // total LDS = 40960 B -> 4 blocks/CU

    const int tid  = threadIdx.x;
    const int lane = tid & 63;
    const int w    = tid >> 6;
    const int l15 = lane & 15, lg = lane >> 4;
    const int l7 = l15 & 7;

    // XCD swizzle (1024 blocks, 128/XCD = 8 bh), bh-major, heavy-qb2-first
    const int logical = (blockIdx.x & 7) * 128 + (blockIdx.x >> 3);
    const int bh  = logical >> 4;
    const int qb2 = 15 - (logical & 15);          // 128-row q block
    const int ktmax = 2 * qb2 + 1;

    const unsigned short* Kbh = Kw + (size_t)bh * (SEQ * 64);
    const unsigned short* Vbh = Vw + (size_t)bh * (64 * SEQ);

    const int qrow0 = w * 16;          // wave's q range within a 64-row sub-tile
    const int prow  = qrow0 + l15;     // this lane's softmax q (sub-tile-local)

    // Q fragments in registers (loop-invariant), sub-tiles A and B
    const unsigned short* QrowA = Qw + (size_t)bh * (SEQ * 64) + (size_t)(qb2 * 128 + prow) * 64;
    const unsigned short* QrowB = QrowA + 64 * 64;
    bf16x8 qA0 = gfrag(QrowA + lg * 8), qA1 = gfrag(QrowA + 32 + lg * 8);
    bf16x8 qB0 = gfrag(QrowB + lg * 8), qB1 = gfrag(QrowB + 32 + lg * 8);

    auto STAGE = [&](int kt2, int bufi) {
#pragma unroll
        for (int is = 0; is < 2; ++is) {
            int e = (is * 256 + tid) * 8;
            int row = e >> 6, c = (e >> 3) & 7;
            int sc = (c ^ (row & 7)) << 3;
            gload_lds16(Kbh + (size_t)kt2 * 4096 + row * 64 + sc, &Ks[bufi][e]);
            gload_lds16(Vbh + (size_t)row * SEQ + kt2 * 64 + sc, &Vs[bufi][e]);
        }
    };

    STAGE(0, 0);

    f32x4 oaccA[4], oaccB[4];
#pragma unroll
    for (int f = 0; f < 4; f++) { oaccA[f] = f32x4{0.f, 0.f, 0.f, 0.f}; oaccB[f] = f32x4{0.f, 0.f, 0.f, 0.f}; }
    float mA = -3.0e38f, lA = 0.f, mB = -3.0e38f, lB = 0.f;

    unsigned short* pbase = &Ps[prow * 64];
    const unsigned short* prd = &Ps[prow * 64];

    __syncthreads();

    for (int kt = 0; kt <= ktmax; ++kt) {
        const int cur = kt & 1;
        if (kt < ktmax) STAGE(kt + 1, cur ^ 1);   // issue-early; drained by end-of-iter barrier

        // process one 64-row q sub-tile against the staged K/V tile
        auto PROC = [&](bf16x8 q0, bf16x8 q1, f32x4* oacc, float& mrun, float& lrun, bool diag) {
            f32x4 st[4];
#pragma unroll
            for (int f = 0; f < 4; f++) st[f] = f32x4{0.f, 0.f, 0.f, 0.f};
            __builtin_amdgcn_s_setprio(1);
#pragma unroll
            for (int ks = 0; ks < 2; ++ks) {
                bf16x8 qk = (ks == 0) ? q0 : q1;
#pragma unroll
                for (int f = 0; f < 4; f++) {
                    bf16x8 kfrag = lds_frag(&Ks[cur][(f * 16 + l15) * 64 + (((ks * 4 + lg) ^ l7) << 3)]);
                    st[f] = __builtin_amdgcn_mfma_f32_16x16x32_bf16(kfrag, qk, st[f], 0, 0, 0);
                }
            }
            __builtin_amdgcn_s_setprio(0);

            if (diag) {
#pragma unroll
                for (int f = 0; f < 4; f++)
#pragma unroll
                    for (int r = 0; r < 4; r++) {
                        int kv = f * 16 + 4 * lg + r;
                        if (kv > prow) st[f][r] = -3.0e38f;
                    }
            }

            // per-q max: 15 in-lane + 2 shuffles
            float pm = fmaxf(fmaxf(fmaxf(st[0][0], st[0][1]), fmaxf(st[0][2], st[0][3])),
                             fmaxf(fmaxf(st[1][0], st[1][1]), fmaxf(st[1][2], st[1][3])));
            pm = fmaxf(pm, fmaxf(fmaxf(fmaxf(st[2][0], st[2][1]), fmaxf(st[2][2], st[2][3])),
                                 fmaxf(fmaxf(st[3][0], st[3][1]), fmaxf(st[3][2], st[3][3]))));
            pm = fmaxf(pm, __shfl_xor(pm, 16));
            pm = fmaxf(pm, __shfl_xor(pm, 32));

            // defer-max (T13)
            if (!__all(pm - mrun <= 8.0f)) {
                float mnew = fmaxf(mrun, pm);
                float sc0 = exp2f(mrun - mnew);
                mrun = mnew;
                lrun *= sc0;
#pragma unroll
                for (int r = 0; r < 4; r++) {
                    float so = __shfl(sc0, lg * 4 + r);
#pragma unroll
                    for (int f = 0; f < 4; f++) oacc[f][r] *= so;
                }
            }

            // exp2 + row-sum
            float lsum = 0.f;
#pragma unroll
            for (int f = 0; f < 4; f++)
#pragma unroll
                for (int r = 0; r < 4; r++) {
                    float e = exp2f(st[f][r] - mrun);
                    st[f][r] = e;
                    lsum += e;
                }
            lsum += __shfl_xor(lsum, 16);
            lsum += __shfl_xor(lsum, 32);
            lrun += lsum;

            // P -> Ps (wave-private rows; in-wave LDS ordering guards reuse)
            {
                const int halfoff = (lg & 1) << 2;
                const int cbase = lg >> 1;
#pragma unroll
                for (int f = 0; f < 4; f++) {
                    uint2 pw;
                    pw.x = cvt_pk_bf16(st[f][0], st[f][1]);
                    pw.y = cvt_pk_bf16(st[f][2], st[f][3]);
                    *(uint2*)(pbase + (((2 * f + cbase) ^ l7) << 3) + halfoff) = pw;
                }
            }

            // O += P V
            __builtin_amdgcn_s_setprio(1);
#pragma unroll
            for (int ks = 0; ks < 2; ++ks) {
                bf16x8 pa = lds_frag(prd + (((ks * 4 + lg) ^ l7) << 3));
#pragma unroll
                for (int f = 0; f < 4; f++) {
                    bf16x8 vb = lds_frag(&Vs[cur][(f * 16 + l15) * 64 + (((ks * 4 + lg) ^ l7) << 3)]);
                    oacc[f] = __builtin_amdgcn_mfma_f32_16x16x32_bf16(pa, vb, oacc[f], 0, 0, 0);
                }
            }
            __builtin_amdgcn_s_setprio(0);
        };

        if (kt <= 2 * qb2) PROC(qA0, qA1, oaccA, mA, lA, kt == 2 * qb2);
        PROC(qB0, qB1, oaccB, mB, lB, kt == ktmax);

        __syncthreads();   // drains prefetch (vmcnt) + guards K/V buffer reuse
    }

    const int b = bh >> 4, h = bh & 15;
#pragma unroll
    for (int r = 0; r < 4; r++) {
        float lrA = __shfl(lA, lg * 4 + r);
        float invA = 1.0f / lrA;
        int sgA = qb2 * 128 + qrow0 + lg * 4 + r;
        unsigned short* orowA = Ow + ((size_t)(b * SEQ + sgA) * DMODEL) + h * 64 + l15;
#pragma unroll
        for (int f = 0; f < 4; f++) orowA[f * 16] = f2bf(oaccA[f][r] * invA);

        float lrB = __shfl(lB, lg * 4 + r);
        float invB = 1.0f / lrB;
        unsigned short* orowB = orowA + (size_t)64 * DMODEL;
#pragma unroll
        for (int f = 0; f < 4; f++) orowB[f * 16] = f2bf(oaccB[f][r] * invB);
    }
}

extern "C" void kernel_launch(void* const* d_in, const int* in_sizes, int n_in,
                              void* d_out, int out_size, void* d_ws, size_t ws_size,
                              hipStream_t stream) {
    const float* x  = (const float*)d_in[0];
    const float* wq = (const float*)d_in[1];
    const float* wk = (const float*)d_in[2];
    const float* wv = (const float*)d_in[3];
    const float* wo = (const float*)d_in[4];

    unsigned short* ws = (unsigned short*)d_ws;
    const size_t MEL = (size_t)8192 * 1024;   // 8M elements
    const size_t WEL = (size_t)1024 * 1024;   // 1M elements
    unsigned short* xb  = ws;
    unsigned short* wqb = xb + MEL;           // 4 weights contiguous: wq|wk|wv|wo
    unsigned short* wob = wqb + 3 * WEL;
    unsigned short* qw  = wob + WEL;
    unsigned short* kw  = qw + MEL;
    unsigned short* vw  = kw + MEL;
    unsigned short* ow  = vw + MEL;

    cvt_f32_bf16<<<8192, 256, 0, stream>>>(x, xb, (int)(MEL / 4));
    cvt_weights<<<4096, 256, 0, stream>>>(wq, wk, wv, wo, wqb);

    gemm_qkv<<<dim3(24, 64), 256, 0, stream>>>(xb, wqb, qw, kw, vw);

    flash_attn<<<1024, 256, 0, stream>>>(qw, kw, vw, ow);

    gemm_out<<<512, 256, 0, stream>>>(ow, wob, (float*)d_out);
}

// Round 7
// 189.997 us; speedup vs baseline: 2.3913x; 1.2154x over previous
//
#include <hip/hip_runtime.h>
#include <stdint.h>

#define NHEAD  16
#define SEQ    2048
#define DMODEL 1024
#define BATCH  4

typedef __attribute__((ext_vector_type(4))) float f32x4;
typedef __attribute__((ext_vector_type(8))) __bf16 bf16x8;
typedef __attribute__((ext_vector_type(8))) unsigned short u16x8;

__device__ __forceinline__ unsigned short f2bf(float f) {
    unsigned int u = __builtin_bit_cast(unsigned int, f);
    u += 0x7FFFu + ((u >> 16) & 1u);   // RNE
    return (unsigned short)(u >> 16);
}

__device__ __forceinline__ unsigned int cvt_pk_bf16(float lo, float hi) {
    unsigned int r;
    asm("v_cvt_pk_bf16_f32 %0, %1, %2" : "=v"(r) : "v"(lo), "v"(hi));
    return r;
}

// async global->LDS, 16B per lane. LDS dest must be wave-uniform base + lane*16.
__device__ __forceinline__ void gload_lds16(const void* g, void* l) {
    __builtin_amdgcn_global_load_lds(
        (const __attribute__((address_space(1))) unsigned int*)(uintptr_t)g,
        (__attribute__((address_space(3))) unsigned int*)(uintptr_t)l,
        16, 0, 0);
}

__device__ __forceinline__ bf16x8 lds_frag(const unsigned short* p) {
    return __builtin_bit_cast(bf16x8, *(const u16x8*)p);
}

__device__ __forceinline__ bf16x8 gfrag(const unsigned short* p) {
    return __builtin_bit_cast(bf16x8, *(const u16x8*)p);
}

// ---------------- fp32 -> bf16 conversion ----------------
__global__ __launch_bounds__(256) void cvt_f32_bf16(const float* __restrict__ src,
                                                    unsigned short* __restrict__ dst, int n4) {
    int i = blockIdx.x * 256 + threadIdx.x;
    if (i < n4) {
        float4 v = ((const float4*)src)[i];
        ushort4 o;
        o.x = f2bf(v.x); o.y = f2bf(v.y); o.z = f2bf(v.z); o.w = f2bf(v.w);
        ((ushort4*)dst)[i] = o;
    }
}

__global__ __launch_bounds__(256) void cvt_weights(const float* __restrict__ w0,
                                                   const float* __restrict__ w1,
                                                   const float* __restrict__ w2,
                                                   const float* __restrict__ w3,
                                                   unsigned short* __restrict__ dst) {
    int which = blockIdx.x >> 10;
    int i = (blockIdx.x & 1023) * 256 + threadIdx.x;
    const float* src = which == 0 ? w0 : which == 1 ? w1 : which == 2 ? w2 : w3;
    unsigned short* d = dst + (size_t)which * 1024 * 1024;
    float4 v = ((const float4*)src)[i];
    ushort4 o;
    o.x = f2bf(v.x); o.y = f2bf(v.y); o.z = f2bf(v.z); o.w = f2bf(v.w);
    ((ushort4*)d)[i] = o;
}

// ---------------- fused QKV GEMM: [Q|K|V] = X(8192x1024) * Wcat(3072x1024)^T ----------------
// grid (24, 64): x = n-tile (0-7 Q, 8-15 K, 16-23 V), y = m-tile
// Q output is pre-scaled by 1/8*log2(e) so flash softmax works directly in log2 domain.
__global__ __launch_bounds__(256) void gemm_qkv(const unsigned short* __restrict__ A,
                                                const unsigned short* __restrict__ Wc,
                                                unsigned short* __restrict__ qw,
                                                unsigned short* __restrict__ kw,
                                                unsigned short* __restrict__ vw) {
    __shared__ __align__(16) unsigned short As[2][128 * 64];
    __shared__ __align__(16) unsigned short Bs[2][128 * 64];

    const int tid  = threadIdx.x;
    const int lane = tid & 63;
    const int wid  = tid >> 6;
    const int wm = wid >> 1, wn = wid & 1;
    const int l15 = lane & 15, lg = lane >> 4;

    const int tn = blockIdx.x;
    const int m0 = blockIdx.y * 128, n0 = tn * 128;

    f32x4 acc[4][4];
#pragma unroll
    for (int i = 0; i < 4; i++)
#pragma unroll
        for (int j = 0; j < 4; j++) acc[i][j] = f32x4{0.f, 0.f, 0.f, 0.f};

    const int e0 = tid * 8;
    auto STAGE = [&](int kk, int bufi) {
#pragma unroll
        for (int is = 0; is < 4; ++is) {
            int e = is * 2048 + e0;
            int row = e >> 6, col = e & 63;
            gload_lds16(A  + (size_t)(m0 + row) * 1024 + kk + col, &As[bufi][e]);
            gload_lds16(Wc + (size_t)(n0 + row) * 1024 + kk + col, &Bs[bufi][e]);
        }
    };

    STAGE(0, 0);
    __syncthreads();

    for (int kk = 0; kk < 1024; kk += 64) {
        const int cur = (kk >> 6) & 1;
        if (kk + 64 < 1024) STAGE(kk + 64, cur ^ 1);
#pragma unroll
        for (int ks = 0; ks < 2; ++ks) {
            bf16x8 a[4], b[4];
#pragma unroll
            for (int f = 0; f < 4; f++) {
                a[f] = lds_frag(&As[cur][(wm * 64 + f * 16 + l15) * 64 + ks * 32 + lg * 8]);
                b[f] = lds_frag(&Bs[cur][(wn * 64 + f * 16 + l15) * 64 + ks * 32 + lg * 8]);
            }
#pragma unroll
            for (int i = 0; i < 4; i++)
#pragma unroll
                for (int j = 0; j < 4; j++)
                    acc[i][j] = __builtin_amdgcn_mfma_f32_16x16x32_bf16(a[i], b[j], acc[i][j], 0, 0, 0);
        }
        __syncthreads();
    }

    if (tn >= 16) {   // V -> (b,h,dk,s) transposed
        unsigned short* out = vw;
#pragma unroll
        for (int i = 0; i < 4; i++)
#pragma unroll
            for (int r = 0; r < 4; r++) {
                int m = m0 + wm * 64 + i * 16 + lg * 4 + r;
                int b = m >> 11, s = m & 2047;
#pragma unroll
                for (int j = 0; j < 4; j++) {
                    int n = n0 + wn * 64 + j * 16 + l15;
                    int h = (n >> 6) & 15, dk = n & 63;
                    out[((size_t)(b * NHEAD + h) * 64 + dk) * SEQ + s] = f2bf(acc[i][j][r]);
                }
            }
    } else {          // Q or K with RoPE -> (b,h,s,dk)
        unsigned short* out = (tn < 8) ? qw : kw;
        const float qscale = (tn < 8) ? 0.18033688011112042f : 1.0f;   // 1/8*log2(e) for Q
        const float L2T = 13.287712379549449f;   // log2(10000)
        float invf[4];
#pragma unroll
        for (int j = 0; j < 4; j++) {
            int idx = j * 16 + l15;          // n % 64
            int t = idx >> 1;
            invf[j] = exp2f(-((float)(2 * t) * (1.0f / 64.0f)) * L2T);
        }
        const int par = l15 & 1;
#pragma unroll
        for (int i = 0; i < 4; i++)
#pragma unroll
            for (int r = 0; r < 4; r++) {
                int m = m0 + wm * 64 + i * 16 + lg * 4 + r;
                int b = m >> 11, s = m & 2047;
                float fs = (float)s;
#pragma unroll
                for (int j = 0; j < 4; j++) {
                    float v = acc[i][j][r];
                    float other = __shfl_xor(v, 1);
                    float sn, cs;
                    __sincosf(fs * invf[j], &sn, &cs);
                    float y = par ? fmaf(v, cs, other * sn) : fmaf(v, cs, -other * sn);
                    y *= qscale;
                    int n = n0 + wn * 64 + j * 16 + l15;
                    int h = (n >> 6) & 15, dk = n & 63;
                    out[((size_t)(b * NHEAD + h) * SEQ + s) * 64 + dk] = f2bf(y);
                }
            }
    }
}

// ---------------- output GEMM: d_out = OW(8192x1024) * Wo(1024x1024)^T, fp32 out ----------------
__global__ __launch_bounds__(256) void gemm_out(const unsigned short* __restrict__ A,
                                                const unsigned short* __restrict__ W,
                                                float* __restrict__ out) {
    __shared__ __align__(16) unsigned short As[2][128 * 64];
    __shared__ __align__(16) unsigned short Bs[2][128 * 64];

    const int tid  = threadIdx.x;
    const int lane = tid & 63;
    const int wid  = tid >> 6;
    const int wm = wid >> 1, wn = wid & 1;
    const int l15 = lane & 15, lg = lane >> 4;

    const int tn = blockIdx.x & 7;
    const int tm = blockIdx.x >> 3;
    const int m0 = tm * 128, n0 = tn * 128;

    f32x4 acc[4][4];
#pragma unroll
    for (int i = 0; i < 4; i++)
#pragma unroll
        for (int j = 0; j < 4; j++) acc[i][j] = f32x4{0.f, 0.f, 0.f, 0.f};

    const int e0 = tid * 8;
    auto STAGE = [&](int kk, int bufi) {
#pragma unroll
        for (int is = 0; is < 4; ++is) {
            int e = is * 2048 + e0;
            int row = e >> 6, col = e & 63;
            gload_lds16(A + (size_t)(m0 + row) * 1024 + kk + col, &As[bufi][e]);
            gload_lds16(W + (size_t)(n0 + row) * 1024 + kk + col, &Bs[bufi][e]);
        }
    };

    STAGE(0, 0);
    __syncthreads();

    for (int kk = 0; kk < 1024; kk += 64) {
        const int cur = (kk >> 6) & 1;
        if (kk + 64 < 1024) STAGE(kk + 64, cur ^ 1);
#pragma unroll
        for (int ks = 0; ks < 2; ++ks) {
            bf16x8 a[4], b[4];
#pragma unroll
            for (int f = 0; f < 4; f++) {
                a[f] = lds_frag(&As[cur][(wm * 64 + f * 16 + l15) * 64 + ks * 32 + lg * 8]);
                b[f] = lds_frag(&Bs[cur][(wn * 64 + f * 16 + l15) * 64 + ks * 32 + lg * 8]);
            }
#pragma unroll
            for (int i = 0; i < 4; i++)
#pragma unroll
                for (int j = 0; j < 4; j++)
                    acc[i][j] = __builtin_amdgcn_mfma_f32_16x16x32_bf16(a[i], b[j], acc[i][j], 0, 0, 0);
        }
        __syncthreads();
    }

#pragma unroll
    for (int i = 0; i < 4; i++)
#pragma unroll
        for (int r = 0; r < 4; r++) {
            int m = m0 + wm * 64 + i * 16 + lg * 4 + r;
            float* orow = out + (size_t)m * 1024 + n0 + wn * 64 + l15;
#pragma unroll
            for (int j = 0; j < 4; j++) orow[j * 16] = acc[i][j][r];
        }
}

// ---------------- causal flash attention: balanced pairing (tile p + tile 31-p) ----------------
// Q,K in (bh, s, dk) (Q pre-scaled by 1/8*log2e); V in (bh, dk, s). Out (b,s,dmodel) bf16.
// Each block processes q-tiles A=p (kv 0..p) and B=31-p (kv 0..31-p) sharing one K/V staging
// stream: every block does exactly 33 tile-PROCs -> perfect static load balance at 1024 blocks.
__global__ __launch_bounds__(256, 4) void flash_attn(const unsigned short* __restrict__ Qw,
                                                     const unsigned short* __restrict__ Kw,
                                                     const unsigned short* __restrict__ Vw,
                                                     unsigned short* __restrict__ Ow) {
    __shared__ __align__(16) unsigned short Ks[2][64 * 64];
    __shared__ __align__(16) unsigned short Vs[2][64 * 64];   // [dk][kv]
    __shared__ __align__(16) unsigned short Ps[64 * 64];      // [q][kv], swizzled, reused A/B
    // total LDS = 40960 B -> 4 blocks/CU

    const int tid  = threadIdx.x;
    const int lane = tid & 63;
    const int w    = tid >> 6;
    const int l15 = lane & 15, lg = lane >> 4;
    const int l7 = l15 & 7;

    // XCD swizzle (1024 blocks -> 128/XCD = 8 bh), bh-major
    const int logical = (blockIdx.x & 7) * 128 + (blockIdx.x >> 3);
    const int bh = logical >> 4;
    const int p  = logical & 15;       // pair index: q-tiles p and 31-p
    const int qbB = 31 - p;            // heavy tile
    const int ktmax = qbB;             // kv tiles 0..31-p

    const unsigned short* Kbh = Kw + (size_t)bh * (SEQ * 64);
    const unsigned short* Vbh = Vw + (size_t)bh * (64 * SEQ);

    const int qrow0 = w * 16;          // wave's q range within a 64-row tile
    const int prow  = qrow0 + l15;     // this lane's softmax q (tile-local)

    // Q fragments in registers (loop-invariant), tiles A (=p) and B (=31-p)
    const unsigned short* QrowA = Qw + (size_t)bh * (SEQ * 64) + (size_t)(p * 64 + prow) * 64;
    const unsigned short* QrowB = Qw + (size_t)bh * (SEQ * 64) + (size_t)(qbB * 64 + prow) * 64;
    bf16x8 qA0 = gfrag(QrowA + lg * 8), qA1 = gfrag(QrowA + 32 + lg * 8);
    bf16x8 qB0 = gfrag(QrowB + lg * 8), qB1 = gfrag(QrowB + 32 + lg * 8);

    auto STAGE = [&](int kt2, int bufi) {
#pragma unroll
        for (int is = 0; is < 2; ++is) {
            int e = (is * 256 + tid) * 8;
            int row = e >> 6, c = (e >> 3) & 7;
            int sc = (c ^ (row & 7)) << 3;
            gload_lds16(Kbh + (size_t)kt2 * 4096 + row * 64 + sc, &Ks[bufi][e]);
            gload_lds16(Vbh + (size_t)row * SEQ + kt2 * 64 + sc, &Vs[bufi][e]);
        }
    };

    STAGE(0, 0);

    f32x4 oaccA[4], oaccB[4];
#pragma unroll
    for (int f = 0; f < 4; f++) { oaccA[f] = f32x4{0.f, 0.f, 0.f, 0.f}; oaccB[f] = f32x4{0.f, 0.f, 0.f, 0.f}; }
    float mA = -3.0e38f, lA = 0.f, mB = -3.0e38f, lB = 0.f;

    unsigned short* pbase = &Ps[prow * 64];
    const unsigned short* prd = &Ps[prow * 64];

    __syncthreads();

    for (int kt = 0; kt <= ktmax; ++kt) {
        const int cur = kt & 1;
        if (kt < ktmax) STAGE(kt + 1, cur ^ 1);   // issue-early; drained by end-of-iter barrier

        // process one 64-row q tile against the staged K/V tile
        auto PROC = [&](bf16x8 q0, bf16x8 q1, f32x4* oacc, float& mrun, float& lrun, bool diag) {
            f32x4 st[4];
#pragma unroll
            for (int f = 0; f < 4; f++) st[f] = f32x4{0.f, 0.f, 0.f, 0.f};
            __builtin_amdgcn_s_setprio(1);
#pragma unroll
            for (int ks = 0; ks < 2; ++ks) {
                bf16x8 qk = (ks == 0) ? q0 : q1;
#pragma unroll
                for (int f = 0; f < 4; f++) {
                    bf16x8 kfrag = lds_frag(&Ks[cur][(f * 16 + l15) * 64 + (((ks * 4 + lg) ^ l7) << 3)]);
                    st[f] = __builtin_amdgcn_mfma_f32_16x16x32_bf16(kfrag, qk, st[f], 0, 0, 0);
                }
            }
            __builtin_amdgcn_s_setprio(0);

            if (diag) {
#pragma unroll
                for (int f = 0; f < 4; f++)
#pragma unroll
                    for (int r = 0; r < 4; r++) {
                        int kv = f * 16 + 4 * lg + r;
                        if (kv > prow) st[f][r] = -3.0e38f;
                    }
            }

            // per-q max: 15 in-lane + 2 shuffles
            float pm = fmaxf(fmaxf(fmaxf(st[0][0], st[0][1]), fmaxf(st[0][2], st[0][3])),
                             fmaxf(fmaxf(st[1][0], st[1][1]), fmaxf(st[1][2], st[1][3])));
            pm = fmaxf(pm, fmaxf(fmaxf(fmaxf(st[2][0], st[2][1]), fmaxf(st[2][2], st[2][3])),
                                 fmaxf(fmaxf(st[3][0], st[3][1]), fmaxf(st[3][2], st[3][3]))));
            pm = fmaxf(pm, __shfl_xor(pm, 16));
            pm = fmaxf(pm, __shfl_xor(pm, 32));

            // defer-max (T13)
            if (!__all(pm - mrun <= 8.0f)) {
                float mnew = fmaxf(mrun, pm);
                float sc0 = exp2f(mrun - mnew);
                mrun = mnew;
                lrun *= sc0;
#pragma unroll
                for (int r = 0; r < 4; r++) {
                    float so = __shfl(sc0, lg * 4 + r);
#pragma unroll
                    for (int f = 0; f < 4; f++) oacc[f][r] *= so;
                }
            }

            // exp2 + row-sum
            float lsum = 0.f;
#pragma unroll
            for (int f = 0; f < 4; f++)
#pragma unroll
                for (int r = 0; r < 4; r++) {
                    float e = exp2f(st[f][r] - mrun);
                    st[f][r] = e;
                    lsum += e;
                }
            lsum += __shfl_xor(lsum, 16);
            lsum += __shfl_xor(lsum, 32);
            lrun += lsum;

            // P -> Ps (wave-private rows; in-wave LDS ordering guards reuse)
            {
                const int halfoff = (lg & 1) << 2;
                const int cbase = lg >> 1;
#pragma unroll
                for (int f = 0; f < 4; f++) {
                    uint2 pw;
                    pw.x = cvt_pk_bf16(st[f][0], st[f][1]);
                    pw.y = cvt_pk_bf16(st[f][2], st[f][3]);
                    *(uint2*)(pbase + (((2 * f + cbase) ^ l7) << 3) + halfoff) = pw;
                }
            }

            // O += P V
            __builtin_amdgcn_s_setprio(1);
#pragma unroll
            for (int ks = 0; ks < 2; ++ks) {
                bf16x8 pa = lds_frag(prd + (((ks * 4 + lg) ^ l7) << 3));
#pragma unroll
                for (int f = 0; f < 4; f++) {
                    bf16x8 vb = lds_frag(&Vs[cur][(f * 16 + l15) * 64 + (((ks * 4 + lg) ^ l7) << 3)]);
                    oacc[f] = __builtin_amdgcn_mfma_f32_16x16x32_bf16(pa, vb, oacc[f], 0, 0, 0);
                }
            }
            __builtin_amdgcn_s_setprio(0);
        };

        if (kt <= p) PROC(qA0, qA1, oaccA, mA, lA, kt == p);
        PROC(qB0, qB1, oaccB, mB, lB, kt == ktmax);

        __syncthreads();   // drains prefetch (vmcnt) + guards K/V buffer reuse
    }

    const int b = bh >> 4, h = bh & 15;
#pragma unroll
    for (int r = 0; r < 4; r++) {
        float lrA = __shfl(lA, lg * 4 + r);
        float invA = 1.0f / lrA;
        int sgA = p * 64 + qrow0 + lg * 4 + r;
        unsigned short* orowA = Ow + ((size_t)(b * SEQ + sgA) * DMODEL) + h * 64 + l15;
#pragma unroll
        for (int f = 0; f < 4; f++) orowA[f * 16] = f2bf(oaccA[f][r] * invA);

        float lrB = __shfl(lB, lg * 4 + r);
        float invB = 1.0f / lrB;
        int sgB = qbB * 64 + qrow0 + lg * 4 + r;
        unsigned short* orowB = Ow + ((size_t)(b * SEQ + sgB) * DMODEL) + h * 64 + l15;
#pragma unroll
        for (int f = 0; f < 4; f++) orowB[f * 16] = f2bf(oaccB[f][r] * invB);
    }
}

extern "C" void kernel_launch(void* const* d_in, const int* in_sizes, int n_in,
                              void* d_out, int out_size, void* d_ws, size_t ws_size,
                              hipStream_t stream) {
    const float* x  = (const float*)d_in[0];
    const float* wq = (const float*)d_in[1];
    const float* wk = (const float*)d_in[2];
    const float* wv = (const float*)d_in[3];
    const float* wo = (const float*)d_in[4];

    unsigned short* ws = (unsigned short*)d_ws;
    const size_t MEL = (size_t)8192 * 1024;   // 8M elements
    const size_t WEL = (size_t)1024 * 1024;   // 1M elements
    unsigned short* xb  = ws;
    unsigned short* wqb = xb + MEL;           // 4 weights contiguous: wq|wk|wv|wo
    unsigned short* wob = wqb + 3 * WEL;
    unsigned short* qw  = wob + WEL;
    unsigned short* kw  = qw + MEL;
    unsigned short* vw  = kw + MEL;
    unsigned short* ow  = vw + MEL;

    cvt_f32_bf16<<<8192, 256, 0, stream>>>(x, xb, (int)(MEL / 4));
    cvt_weights<<<4096, 256, 0, stream>>>(wq, wk, wv, wo, wqb);

    gemm_qkv<<<dim3(24, 64), 256, 0, stream>>>(xb, wqb, qw, kw, vw);

    flash_attn<<<1024, 256, 0, stream>>>(qw, kw, vw, ow);

    gemm_out<<<512, 256, 0, stream>>>(ow, wob, (float*)d_out);
}